// Round 2
// baseline (20095.515 us; speedup 1.0000x reference)
//
#include <hip/hip_runtime.h>
#include <math.h>

#define NB 64    // batch
#define TT 512   // time steps
#define IN 128   // input dim
#define HD 512   // hidden dim
#define KSL 64   // k-slice (64 k-values = 16KB per h buffer slice)
#define NSL (HD / KSL)

__device__ __forceinline__ float sigf(float x) { return 1.0f / (1.0f + expf(-x)); }

// ws layout (floats): h0T [2][HD][NB] | h2T [2][HD][NB] | c0 [HD][NB] | c2 [HD][NB]
// Pipeline step s: layer0 computes h0_s (from h0_{s-1}), layer1 computes h2_{s-1}
// (from h0_{s-1} and h2_{s-2}). Same indexing as the verified Round-0 kernel.

__global__ __launch_bounds__(512) void lstm_step(
    const float* __restrict__ x,
    const float* __restrict__ Wih0, const float* __restrict__ Whh0,
    const float* __restrict__ bih0, const float* __restrict__ bhh0,
    const float* __restrict__ Wih1, const float* __restrict__ Whh1,
    const float* __restrict__ bih1, const float* __restrict__ bhh1,
    float* __restrict__ ws, int s)
{
    // 4 x 16KB slice buffers = 64KB static LDS (1 block/CU, 8 waves = 2/SIMD)
    __shared__ float h0buf[2][KSL][NB];
    __shared__ float h2buf[2][KSL][NB];

    float* h0T = ws;
    float* h2T = ws + 2*HD*NB;
    float* c0  = ws + 4*HD*NB;
    float* c2  = ws + 5*HD*NB;

    const int tid = threadIdx.x;
    const int b   = tid & 63;         // lane = batch
    const int w   = tid >> 6;         // wave 0..7 encodes (gate, unit-local)
    const int g   = w >> 1;           // gate 0..3
    const int ul  = w & 1;            // local unit 0/1
    const int u   = blockIdx.x*2 + ul;
    const int r   = g*HD + u;         // gate-row in [0,2048)

    const int cur = s & 1, prev = cur ^ 1;
    const float* __restrict__ h0prev = h0T + prev*HD*NB;  // h0_{s-1}
    const float* __restrict__ h2prev = h2T + cur*HD*NB;   // h2_{s-2}

    float acc0 = bih0[r] + bhh0[r];   // layer0 gate-row r, batch b
    float acc1 = bih1[r] + bhh1[r];   // layer1 gate-row r, batch b

    // ---- issue slice-0 stage loads early (land under x-part compute) ----
    const float4* __restrict__ g0 = (const float4*)h0prev;  // [8192] float4
    const float4* __restrict__ g2 = (const float4*)h2prev;
    float4 s0a = g0[tid],       s0b = g0[512 + tid];
    float4 s2a = g2[tid],       s2b = g2[512 + tid];

    // ---- layer0 input part: x_t . Wih0[r,:]  (K=128, per-lane global x) ----
    if (s < TT) {
        const float4* __restrict__ xq = (const float4*)(x + ((size_t)b*TT + s)*IN);
        const float4* __restrict__ wq = (const float4*)(Wih0 + (size_t)r*IN);
        #pragma unroll
        for (int i = 0; i < IN/4; ++i) {
            float4 xv = xq[i], wv = wq[i];
            acc0 += xv.x*wv.x + xv.y*wv.y + xv.z*wv.z + xv.w*wv.w;
        }
    }

    // write slice 0 into buffer 0
    {
        float4* d0 = (float4*)&h0buf[0][0][0];
        float4* d2 = (float4*)&h2buf[0][0][0];
        d0[tid] = s0a; d0[512+tid] = s0b;
        d2[tid] = s2a; d2[512+tid] = s2b;
    }
    __syncthreads();

    const float4* __restrict__ wh0 = (const float4*)(Whh0 + (size_t)r*HD);
    const float4* __restrict__ wi1 = (const float4*)(Wih1 + (size_t)r*HD);
    const float4* __restrict__ wh1 = (const float4*)(Whh1 + (size_t)r*HD);

    for (int sl = 0; sl < NSL; ++sl) {
        const int cb = sl & 1;
        // issue next slice's global loads before computing this one (T14)
        if (sl + 1 < NSL) {
            const int base = (sl+1)*1024;
            s0a = g0[base + tid]; s0b = g0[base + 512 + tid];
            s2a = g2[base + tid]; s2b = g2[base + 512 + tid];
        }
        const float* __restrict__ hb0 = &h0buf[cb][0][0];
        const float* __restrict__ hb2 = &h2buf[cb][0][0];
        const int kq0 = sl*(KSL/4);
        #pragma unroll 8
        for (int k4 = 0; k4 < KSL/4; ++k4) {
            float4 w0 = wh0[kq0 + k4];   // Whh0 row r  (layer0 recurrent)
            float4 w1 = wi1[kq0 + k4];   // Wih1 row r  (layer1 input)
            float4 w2 = wh1[kq0 + k4];   // Whh1 row r  (layer1 recurrent)
            const float* p0 = hb0 + (k4*4)*NB + b;   // h0 slice, stride-NB (2-way bank = free)
            const float* p2 = hb2 + (k4*4)*NB + b;
            float h00=p0[0], h01=p0[NB], h02=p0[2*NB], h03=p0[3*NB];
            float q0 =p2[0], q1 =p2[NB], q2 =p2[2*NB], q3 =p2[3*NB];
            acc0 += h00*w0.x + h01*w0.y + h02*w0.z + h03*w0.w;
            acc1 += h00*w1.x + h01*w1.y + h02*w1.z + h03*w1.w;
            acc1 += q0*w2.x + q1*w2.y + q2*w2.z + q3*w2.w;
        }
        // write-late: staged regs -> LDS for next slice, then barrier
        if (sl + 1 < NSL) {
            const int nb_ = (sl+1)&1;
            float4* d0 = (float4*)&h0buf[nb_][0][0];
            float4* d2 = (float4*)&h2buf[nb_][0][0];
            d0[tid] = s0a; d0[512+tid] = s0b;
            d2[tid] = s2a; d2[512+tid] = s2b;
        }
        __syncthreads();
    }

    // ---- gate exchange (overlay on h0buf[0], free after last barrier) ----
    float* gl = &h0buf[0][0][0];
    gl[w*64 + b]       = acc0;   // layer0 gates, idx (g*2+ul)*64+b
    gl[512 + w*64 + b] = acc1;   // layer1 gates
    __syncthreads();

    if (tid < 256) {
        const int layer = tid >> 7;
        const int u2    = (tid >> 6) & 1;
        const int bb    = tid & 63;
        const int ug    = blockIdx.x*2 + u2;
        const float* gs = gl + layer*512;
        float gi = gs[((0*2)|u2)*64 + bb];
        float gf = gs[((1*2)|u2)*64 + bb];
        float gc = gs[((2*2)|u2)*64 + bb];
        float go = gs[((3*2)|u2)*64 + bb];
        if (layer == 0) {
            if (s < TT) {
                float iv=sigf(gi), fv=sigf(gf), cv=tanhf(gc), ov=sigf(go);
                float cp = c0[ug*NB + bb];
                float cn = fv*cp + iv*cv;
                c0[ug*NB + bb] = cn;
                h0T[cur*HD*NB + ug*NB + bb] = ov*tanhf(cn);
            }
        } else {
            if (s >= 1) {
                float iv=sigf(gi), fv=sigf(gf), cv=tanhf(gc), ov=sigf(go);
                float cp = c2[ug*NB + bb];
                float cn = fv*cp + iv*cv;
                c2[ug*NB + bb] = cn;
                h2T[prev*HD*NB + ug*NB + bb] = ov*tanhf(cn);  // h2_{s-1}
            }
        }
    }
}

__global__ __launch_bounds__(64) void fc_kernel(
    const float* __restrict__ ws, const float* __restrict__ fcW,
    const float* __restrict__ fcb, float* __restrict__ out)
{
    const float* __restrict__ h2last = ws + 2*HD*NB + ((TT-1)&1)*HD*NB;
    const int o = blockIdx.x;    // 0..23
    const int b = threadIdx.x;   // 0..63
    float acc = fcb[o];
    const float* __restrict__ wr = fcW + (size_t)o*HD;
    #pragma unroll 8
    for (int k = 0; k < HD; ++k)
        acc += h2last[k*NB + b] * wr[k];
    out[b*24 + o] = acc;
}

extern "C" void kernel_launch(void* const* d_in, const int* in_sizes, int n_in,
                              void* d_out, int out_size, void* d_ws, size_t ws_size,
                              hipStream_t stream)
{
    const float* x    = (const float*)d_in[0];
    const float* Wih0 = (const float*)d_in[1];
    const float* Whh0 = (const float*)d_in[2];
    const float* bih0 = (const float*)d_in[3];
    const float* bhh0 = (const float*)d_in[4];
    const float* Wih1 = (const float*)d_in[5];
    const float* Whh1 = (const float*)d_in[6];
    const float* bih1 = (const float*)d_in[7];
    const float* bhh1 = (const float*)d_in[8];
    const float* fcW  = (const float*)d_in[9];
    const float* fcb  = (const float*)d_in[10];
    float* ws = (float*)d_ws;

    hipMemsetAsync(d_ws, 0, (size_t)6*HD*NB*sizeof(float), stream);

    for (int s = 0; s <= TT; ++s)
        lstm_step<<<dim3(256), dim3(512), 0, stream>>>(
            x, Wih0, Whh0, bih0, bhh0, Wih1, Whh1, bih1, bhh1, ws, s);

    fc_kernel<<<dim3(24), dim3(64), 0, stream>>>(ws, fcW, fcb, (float*)d_out);
}

// Round 3
// 19053.400 us; speedup vs baseline: 1.0547x; 1.0547x over previous
//
#include <hip/hip_runtime.h>
#include <math.h>

#define NB 64      // total batch
#define TT 512     // time steps
#define IN 128     // input dim
#define HD 512     // hidden dim
#define BGN 4      // batch groups
#define BGB 16     // batches per group
#define RBN 64     // row-blocks per batch group  (BGN*RBN = 256 blocks)

__device__ __forceinline__ float sigf(float x) { return 1.0f / (1.0f + expf(-x)); }
__device__ __forceinline__ float dot4(float4 a, float4 b) {
    return a.x*b.x + a.y*b.y + a.z*b.z + a.w*b.w;
}

// 6-step butterfly over 64 lanes: on entry lane l holds partials A[j] (j=0..63,
// its k-slice's contribution to output j). On exit returns full sum for j = l.
// Invariant: after s steps, lane l holds, at index i, the sum over the 2^s
// lanes {l ^ span} of A_orig[(i<<s)|(l & ((1<<s)-1))].
__device__ __forceinline__ float wave_reduce64(float* A, int l) {
    #pragma unroll
    for (int s = 0; s < 6; ++s) {
        const int m = 1 << s;
        const bool bit = (l >> s) & 1;
        const int cnt = 64 >> (s + 1);
        #pragma unroll
        for (int i = 0; i < cnt; ++i) {
            float send = bit ? A[2*i]     : A[2*i + 1];  // what the peer keeps
            float keep = bit ? A[2*i + 1] : A[2*i];      // index with (idx&1)==bit
            float recv = __shfl_xor(send, m, 64);
            A[i] = keep + recv;
        }
    }
    return A[0];
}

// ws layout (floats): h0T[2][HD][NB] | h2T[2][HD][NB] | flags (ints, 64B-strided)
// Pipeline step s: L0 computes h0_s from h0_{s-1}; L1 computes h2_{s-1} from
// h0_{s-1} and h2_{s-2}.  cur=s&1: read h0T[cur^1], h2T[cur]; write h0T[cur],
// h2T[cur^1]  (identical to the verified Round-0 convention).
__global__ __launch_bounds__(512, 2) void lstm_persist(
    const float* __restrict__ x,
    const float* __restrict__ Wih0, const float* __restrict__ Whh0,
    const float* __restrict__ bih0, const float* __restrict__ bhh0,
    const float* __restrict__ Wih1, const float* __restrict__ Whh1,
    const float* __restrict__ bih1, const float* __restrict__ bhh1,
    const float* __restrict__ fcW, const float* __restrict__ fcb,
    float* __restrict__ ws, float* __restrict__ out)
{
    __shared__ float x_lds[BGB][IN];    // 8 KB
    __shared__ float h0_lds[BGB][HD];   // 32 KB   [b][u'] transposed
    __shared__ float h2_lds[BGB][HD];   // 32 KB

    const int tid = threadIdx.x;
    const int l   = tid & 63;          // lane
    const int w   = tid >> 6;          // wave 0..7
    const int bg  = blockIdx.x & 3;    // batch group
    const int rb  = blockIdx.x >> 2;   // row-block 0..63
    const int u   = rb * 8 + w;        // unit owned by this wave (both layers)
    const int bg16 = bg * BGB;
    const int bl  = l & 15;            // state-batch lane

    float* h0T = ws;                       // [2][HD][NB]
    float* h2T = ws + 2 * HD * NB;         // [2][HD][NB]
    int*  flags = (int*)(ws + 4 * HD * NB);

    // ---------------- prologue: weights -> registers (once) ----------------
    // lane l owns k = j*256 + l*4 + e (j=0,1; e=0..3) of each gate row, plus
    // k = l*2 + e of the Wih0 row.
    float4 w0h[4][2], w1i[4][2], w1h[4][2];
    float2 w0x[4];
    #pragma unroll
    for (int g = 0; g < 4; ++g) {
        const size_t r = (size_t)g * HD + u;
        #pragma unroll
        for (int j = 0; j < 2; ++j) {
            w0h[g][j] = *(const float4*)(Whh0 + r * HD + j * 256 + l * 4);
            w1i[g][j] = *(const float4*)(Wih1 + r * HD + j * 256 + l * 4);
            w1h[g][j] = *(const float4*)(Whh1 + r * HD + j * 256 + l * 4);
        }
        w0x[g] = *(const float2*)(Wih0 + r * IN + l * 2);
    }
    const float b0i = bih0[0*HD+u] + bhh0[0*HD+u];
    const float b0f = bih0[1*HD+u] + bhh0[1*HD+u];
    const float b0c = bih0[2*HD+u] + bhh0[2*HD+u];
    const float b0o = bih0[3*HD+u] + bhh0[3*HD+u];
    const float b1i = bih1[0*HD+u] + bhh1[0*HD+u];
    const float b1f = bih1[1*HD+u] + bhh1[1*HD+u];
    const float b1c = bih1[2*HD+u] + bhh1[2*HD+u];
    const float b1o = bih1[3*HD+u] + bhh1[3*HD+u];
    const float bias0 = (l & 32) ? ((l & 16) ? b0o : b0c) : ((l & 16) ? b0f : b0i);
    const float bias1 = (l & 32) ? ((l & 16) ? b1o : b1c) : ((l & 16) ? b1f : b1i);

    float c0r = 0.0f, c2r = 0.0f;      // cell state, valid on lanes 0..15

    int* myflag = flags + bg * 16;     // 64B-strided

    for (int s = 0; s <= TT; ++s) {
        // ---- batch-group barrier: wait for all 64 blocks to finish step s-1 ----
        const int target = RBN * s;
        if (s > 0) {
            int spins = 0;
            while (__hip_atomic_load(myflag, __ATOMIC_RELAXED,
                                     __HIP_MEMORY_SCOPE_AGENT) < target) {
                __builtin_amdgcn_s_sleep(2);
                if (++spins > (1 << 20)) break;   // bounded: bug -> wrong, not hang
            }
            (void)__hip_atomic_load(myflag, __ATOMIC_ACQUIRE,
                                    __HIP_MEMORY_SCOPE_AGENT);
        }

        const int cur = s & 1;
        const float* h0prev = h0T + (cur ^ 1) * HD * NB;  // h0_{s-1}
        const float* h2prev = h2T + cur * HD * NB;        // h2_{s-2}

        // ---- stage h0,h2 (transposed [b][u']) and x into LDS ----
        {
            const float* s0 = h0prev + (size_t)tid * NB + bg16;
            const float* s2 = h2prev + (size_t)tid * NB + bg16;
            float4 q0 = *(const float4*)(s0 + 0),  q1 = *(const float4*)(s0 + 4);
            float4 q2 = *(const float4*)(s0 + 8),  q3 = *(const float4*)(s0 + 12);
            float4 p0 = *(const float4*)(s2 + 0),  p1 = *(const float4*)(s2 + 4);
            float4 p2 = *(const float4*)(s2 + 8),  p3 = *(const float4*)(s2 + 12);
            h0_lds[ 0][tid]=q0.x; h0_lds[ 1][tid]=q0.y; h0_lds[ 2][tid]=q0.z; h0_lds[ 3][tid]=q0.w;
            h0_lds[ 4][tid]=q1.x; h0_lds[ 5][tid]=q1.y; h0_lds[ 6][tid]=q1.z; h0_lds[ 7][tid]=q1.w;
            h0_lds[ 8][tid]=q2.x; h0_lds[ 9][tid]=q2.y; h0_lds[10][tid]=q2.z; h0_lds[11][tid]=q2.w;
            h0_lds[12][tid]=q3.x; h0_lds[13][tid]=q3.y; h0_lds[14][tid]=q3.z; h0_lds[15][tid]=q3.w;
            h2_lds[ 0][tid]=p0.x; h2_lds[ 1][tid]=p0.y; h2_lds[ 2][tid]=p0.z; h2_lds[ 3][tid]=p0.w;
            h2_lds[ 4][tid]=p1.x; h2_lds[ 5][tid]=p1.y; h2_lds[ 6][tid]=p1.z; h2_lds[ 7][tid]=p1.w;
            h2_lds[ 8][tid]=p2.x; h2_lds[ 9][tid]=p2.y; h2_lds[10][tid]=p2.z; h2_lds[11][tid]=p2.w;
            h2_lds[12][tid]=p3.x; h2_lds[13][tid]=p3.y; h2_lds[14][tid]=p3.z; h2_lds[15][tid]=p3.w;
            if (s < TT) {
                const int bb = tid >> 5, ii = (tid & 31) * 4;
                *(float4*)&x_lds[bb][ii] =
                    *(const float4*)(x + ((size_t)(bg16 + bb) * TT + s) * IN + ii);
            }
        }
        __syncthreads();

        float r0 = 0.0f, r1 = 0.0f;

        // ---- layer0: gates for (unit u, all 16 batches) ----
        if (s < TT) {
            float A[64];
            #pragma unroll
            for (int j = 0; j < 64; ++j) A[j] = 0.0f;
            #pragma unroll
            for (int b = 0; b < BGB; ++b) {
                float4 ha = *(const float4*)&h0_lds[b][l * 4];
                float4 hb = *(const float4*)&h0_lds[b][256 + l * 4];
                float2 xv = *(const float2*)&x_lds[b][l * 2];
                #pragma unroll
                for (int g = 0; g < 4; ++g) {
                    A[g * 16 + b] += dot4(w0h[g][0], ha) + dot4(w0h[g][1], hb)
                                   + w0x[g].x * xv.x + w0x[g].y * xv.y;
                }
            }
            r0 = wave_reduce64(A, l) + bias0;
        }
        // ---- layer1: gates for (unit u, all 16 batches) ----
        if (s >= 1) {
            float A[64];
            #pragma unroll
            for (int j = 0; j < 64; ++j) A[j] = 0.0f;
            #pragma unroll
            for (int b = 0; b < BGB; ++b) {
                float4 ha = *(const float4*)&h0_lds[b][l * 4];
                float4 hb = *(const float4*)&h0_lds[b][256 + l * 4];
                float4 qa = *(const float4*)&h2_lds[b][l * 4];
                float4 qb = *(const float4*)&h2_lds[b][256 + l * 4];
                #pragma unroll
                for (int g = 0; g < 4; ++g) {
                    A[g * 16 + b] += dot4(w1i[g][0], ha) + dot4(w1i[g][1], hb)
                                   + dot4(w1h[g][0], qa) + dot4(w1h[g][1], qb);
                }
            }
            r1 = wave_reduce64(A, l) + bias1;
        }

        // ---- gather gates to lanes 0..15 (shfl by ALL lanes), update state ----
        float gi0 = __shfl(r0, bl,      64);
        float gf0 = __shfl(r0, bl + 16, 64);
        float gc0 = __shfl(r0, bl + 32, 64);
        float go0 = __shfl(r0, bl + 48, 64);
        float gi1 = __shfl(r1, bl,      64);
        float gf1 = __shfl(r1, bl + 16, 64);
        float gc1 = __shfl(r1, bl + 32, 64);
        float go1 = __shfl(r1, bl + 48, 64);
        if (l < 16) {
            if (s < TT) {
                float cn = sigf(gf0) * c0r + sigf(gi0) * tanhf(gc0);
                c0r = cn;
                h0T[cur * HD * NB + (size_t)u * NB + bg16 + bl] = sigf(go0) * tanhf(cn);
            }
            if (s >= 1) {
                float cn = sigf(gf1) * c2r + sigf(gi1) * tanhf(gc1);
                c2r = cn;
                h2T[(cur ^ 1) * HD * NB + (size_t)u * NB + bg16 + bl] = sigf(go1) * tanhf(cn);
            }
        }

        // ---- arrive ----
        __syncthreads();
        if (tid == 0) {
            __threadfence();
            __hip_atomic_fetch_add(myflag, 1, __ATOMIC_RELEASE,
                                   __HIP_MEMORY_SCOPE_AGENT);
        }
    }

    // ---------------- FC tail: one block per batch group ----------------
    if (rb != 0) return;
    {
        const int target = RBN * (TT + 1);
        int spins = 0;
        while (__hip_atomic_load(myflag, __ATOMIC_RELAXED,
                                 __HIP_MEMORY_SCOPE_AGENT) < target) {
            __builtin_amdgcn_s_sleep(2);
            if (++spins > (1 << 20)) break;
        }
        (void)__hip_atomic_load(myflag, __ATOMIC_ACQUIRE, __HIP_MEMORY_SCOPE_AGENT);

        // h2[TT-1] lives in buffer (TT-1)&1 = 1
        const float* hsrc = h2T + 1 * HD * NB + (size_t)tid * NB + bg16;
        float4 q0 = *(const float4*)(hsrc + 0),  q1 = *(const float4*)(hsrc + 4);
        float4 q2 = *(const float4*)(hsrc + 8),  q3 = *(const float4*)(hsrc + 12);
        h2_lds[ 0][tid]=q0.x; h2_lds[ 1][tid]=q0.y; h2_lds[ 2][tid]=q0.z; h2_lds[ 3][tid]=q0.w;
        h2_lds[ 4][tid]=q1.x; h2_lds[ 5][tid]=q1.y; h2_lds[ 6][tid]=q1.z; h2_lds[ 7][tid]=q1.w;
        h2_lds[ 8][tid]=q2.x; h2_lds[ 9][tid]=q2.y; h2_lds[10][tid]=q2.z; h2_lds[11][tid]=q2.w;
        h2_lds[12][tid]=q3.x; h2_lds[13][tid]=q3.y; h2_lds[14][tid]=q3.z; h2_lds[15][tid]=q3.w;
        __syncthreads();

        const int bb = tid >> 5, oo = tid & 31;
        if (oo < 24) {
            float acc = fcb[oo];
            const float4* hrow = (const float4*)&h2_lds[bb][0];
            const float4* wrow = (const float4*)(fcW + (size_t)oo * HD);
            #pragma unroll 8
            for (int q = 0; q < HD / 4; ++q) acc += dot4(hrow[q], wrow[q]);
            out[(size_t)(bg16 + bb) * 24 + oo] = acc;
        }
    }
}

extern "C" void kernel_launch(void* const* d_in, const int* in_sizes, int n_in,
                              void* d_out, int out_size, void* d_ws, size_t ws_size,
                              hipStream_t stream)
{
    const float* x    = (const float*)d_in[0];
    const float* Wih0 = (const float*)d_in[1];
    const float* Whh0 = (const float*)d_in[2];
    const float* bih0 = (const float*)d_in[3];
    const float* bhh0 = (const float*)d_in[4];
    const float* Wih1 = (const float*)d_in[5];
    const float* Whh1 = (const float*)d_in[6];
    const float* bih1 = (const float*)d_in[7];
    const float* bhh1 = (const float*)d_in[8];
    const float* fcW  = (const float*)d_in[9];
    const float* fcb  = (const float*)d_in[10];

    // zero h ping-pong buffers + flags every call (graph-capture-safe)
    hipMemsetAsync(d_ws, 0, (size_t)(4 * HD * NB) * sizeof(float) + 1024, stream);

    lstm_persist<<<dim3(BGN * RBN), dim3(512), 0, stream>>>(
        x, Wih0, Whh0, bih0, bhh0, Wih1, Whh1, bih1, bhh1, fcW, fcb,
        (float*)d_ws, (float*)d_out);
}

// Round 4
// 12456.558 us; speedup vs baseline: 1.6132x; 1.5296x over previous
//
#include <hip/hip_runtime.h>
#include <math.h>

#define NB 64      // total batch
#define TT 512     // time steps
#define IN 128     // input dim
#define HD 512     // hidden dim
#define BGN 4      // batch groups
#define BGB 16     // batches per group
#define RBN 64     // row-blocks per batch group  (BGN*RBN = 256 blocks)

__device__ __forceinline__ float sigf(float x) { return 1.0f / (1.0f + expf(-x)); }
__device__ __forceinline__ float dot4(float4 a, float4 b) {
    return a.x*b.x + a.y*b.y + a.z*b.z + a.w*b.w;
}

// 6-step butterfly over 64 lanes: on entry lane l holds partials A[j] (j=0..63,
// its k-slice's contribution to output j). On exit returns full sum for j = l.
__device__ __forceinline__ float wave_reduce64(float* A, int l) {
    #pragma unroll
    for (int s = 0; s < 6; ++s) {
        const int m = 1 << s;
        const bool bit = (l >> s) & 1;
        const int cnt = 64 >> (s + 1);
        #pragma unroll
        for (int i = 0; i < cnt; ++i) {
            float send = bit ? A[2*i]     : A[2*i + 1];
            float keep = bit ? A[2*i + 1] : A[2*i];
            float recv = __shfl_xor(send, m, 64);
            A[i] = keep + recv;
        }
    }
    return A[0];
}

// ws layout (floats): h0T[2][HD][NB] | h2T[2][HD][NB] | flags (ints, 64B-strided)
// Pipeline step s: L0 computes h0_s from h0_{s-1}; L1 computes h2_{s-1} from
// h0_{s-1} and h2_{s-2}.  cur=s&1: read h0T[cur^1], h2T[cur]; write h0T[cur],
// h2T[cur^1]  (identical to the verified Round-0/2 convention).
__global__ __launch_bounds__(512) void lstm_persist(
    const float* __restrict__ x,
    const float* __restrict__ Wih0, const float* __restrict__ Whh0,
    const float* __restrict__ bih0, const float* __restrict__ bhh0,
    const float* __restrict__ Wih1, const float* __restrict__ Whh1,
    const float* __restrict__ bih1, const float* __restrict__ bhh1,
    const float* __restrict__ fcW, const float* __restrict__ fcb,
    float* __restrict__ ws, float* __restrict__ out)
{
    __shared__ float x_lds[BGB][IN];    // 8 KB
    __shared__ float h0_lds[BGB][HD];   // 32 KB   [b][u'] transposed
    __shared__ float h2_lds[BGB][HD];   // 32 KB

    const int tid = threadIdx.x;
    const int l   = tid & 63;          // lane
    const int w   = tid >> 6;          // wave 0..7
    const int bg  = blockIdx.x & 3;    // batch group
    const int rb  = blockIdx.x >> 2;   // row-block 0..63
    const int u   = rb * 8 + w;        // unit owned by this wave (both layers)
    const int bg16 = bg * BGB;
    const int bl  = l & 15;            // state-batch lane

    float* h0T = ws;                       // [2][HD][NB]
    float* h2T = ws + 2 * HD * NB;         // [2][HD][NB]
    int*  flags = (int*)(ws + 4 * HD * NB);

    // ---------------- prologue: weights -> registers (once) ----------------
    // lane l owns k = j*256 + l*4 + e (j=0,1; e=0..3) of each gate row, plus
    // k = l*2 + e of the Wih0 row.
    float4 w0h[4][2], w1i[4][2], w1h[4][2];
    float2 w0x[4];
    #pragma unroll
    for (int g = 0; g < 4; ++g) {
        const size_t r = (size_t)g * HD + u;
        #pragma unroll
        for (int j = 0; j < 2; ++j) {
            w0h[g][j] = *(const float4*)(Whh0 + r * HD + j * 256 + l * 4);
            w1i[g][j] = *(const float4*)(Wih1 + r * HD + j * 256 + l * 4);
            w1h[g][j] = *(const float4*)(Whh1 + r * HD + j * 256 + l * 4);
        }
        w0x[g] = *(const float2*)(Wih0 + r * IN + l * 2);
    }
    const float b0i = bih0[0*HD+u] + bhh0[0*HD+u];
    const float b0f = bih0[1*HD+u] + bhh0[1*HD+u];
    const float b0c = bih0[2*HD+u] + bhh0[2*HD+u];
    const float b0o = bih0[3*HD+u] + bhh0[3*HD+u];
    const float b1i = bih1[0*HD+u] + bhh1[0*HD+u];
    const float b1f = bih1[1*HD+u] + bhh1[1*HD+u];
    const float b1c = bih1[2*HD+u] + bhh1[2*HD+u];
    const float b1o = bih1[3*HD+u] + bhh1[3*HD+u];
    const float bias0 = (l & 32) ? ((l & 16) ? b0o : b0c) : ((l & 16) ? b0f : b0i);
    const float bias1 = (l & 32) ? ((l & 16) ? b1o : b1c) : ((l & 16) ? b1f : b1i);

    float c0r = 0.0f, c2r = 0.0f;      // cell state, valid on lanes 0..15

    int* myflag = flags + bg * 16;     // 64B-strided

    for (int s = 0; s <= TT; ++s) {
        // ---- T14: issue x load for step s before the barrier (x is input) ----
        float4 xpf;
        const int xb = tid >> 5, xi = (tid & 31) * 4;
        if (s < TT)
            xpf = *(const float4*)(x + ((size_t)(bg16 + xb) * TT + s) * IN + xi);

        // ---- batch-group barrier: single poller per block ----
        const int target = RBN * s;
        if (s > 0) {
            if (tid == 0) {
                int spins = 0;
                while (__hip_atomic_load(myflag, __ATOMIC_RELAXED,
                                         __HIP_MEMORY_SCOPE_AGENT) < target) {
                    __builtin_amdgcn_s_sleep(8);
                    if (++spins > (1 << 22)) break;   // bounded: bug -> wrong, not hang
                }
                (void)__hip_atomic_load(myflag, __ATOMIC_ACQUIRE,
                                        __HIP_MEMORY_SCOPE_AGENT);
            }
            __syncthreads();   // release whole block; acquire's cache-inv is CU-wide
        }

        const int cur = s & 1;
        const float* h0prev = h0T + (cur ^ 1) * HD * NB;  // h0_{s-1}
        const float* h2prev = h2T + cur * HD * NB;        // h2_{s-2}

        // ---- stage h0,h2 (transposed [b][u']) and x into LDS ----
        {
            const float* s0 = h0prev + (size_t)tid * NB + bg16;
            const float* s2 = h2prev + (size_t)tid * NB + bg16;
            float4 q0 = *(const float4*)(s0 + 0),  q1 = *(const float4*)(s0 + 4);
            float4 q2 = *(const float4*)(s0 + 8),  q3 = *(const float4*)(s0 + 12);
            float4 p0 = *(const float4*)(s2 + 0),  p1 = *(const float4*)(s2 + 4);
            float4 p2 = *(const float4*)(s2 + 8),  p3 = *(const float4*)(s2 + 12);
            h0_lds[ 0][tid]=q0.x; h0_lds[ 1][tid]=q0.y; h0_lds[ 2][tid]=q0.z; h0_lds[ 3][tid]=q0.w;
            h0_lds[ 4][tid]=q1.x; h0_lds[ 5][tid]=q1.y; h0_lds[ 6][tid]=q1.z; h0_lds[ 7][tid]=q1.w;
            h0_lds[ 8][tid]=q2.x; h0_lds[ 9][tid]=q2.y; h0_lds[10][tid]=q2.z; h0_lds[11][tid]=q2.w;
            h0_lds[12][tid]=q3.x; h0_lds[13][tid]=q3.y; h0_lds[14][tid]=q3.z; h0_lds[15][tid]=q3.w;
            h2_lds[ 0][tid]=p0.x; h2_lds[ 1][tid]=p0.y; h2_lds[ 2][tid]=p0.z; h2_lds[ 3][tid]=p0.w;
            h2_lds[ 4][tid]=p1.x; h2_lds[ 5][tid]=p1.y; h2_lds[ 6][tid]=p1.z; h2_lds[ 7][tid]=p1.w;
            h2_lds[ 8][tid]=p2.x; h2_lds[ 9][tid]=p2.y; h2_lds[10][tid]=p2.z; h2_lds[11][tid]=p2.w;
            h2_lds[12][tid]=p3.x; h2_lds[13][tid]=p3.y; h2_lds[14][tid]=p3.z; h2_lds[15][tid]=p3.w;
            if (s < TT)
                *(float4*)&x_lds[xb][xi] = xpf;
        }
        __syncthreads();

        float r0 = 0.0f, r1 = 0.0f;

        // ---- layer0: gates for (unit u, all 16 batches) ----
        if (s < TT) {
            float A[64];
            #pragma unroll
            for (int j = 0; j < 64; ++j) A[j] = 0.0f;
            #pragma unroll
            for (int b = 0; b < BGB; ++b) {
                float4 ha = *(const float4*)&h0_lds[b][l * 4];
                float4 hb = *(const float4*)&h0_lds[b][256 + l * 4];
                float2 xv = *(const float2*)&x_lds[b][l * 2];
                #pragma unroll
                for (int g = 0; g < 4; ++g) {
                    A[g * 16 + b] += dot4(w0h[g][0], ha) + dot4(w0h[g][1], hb)
                                   + w0x[g].x * xv.x + w0x[g].y * xv.y;
                }
            }
            r0 = wave_reduce64(A, l) + bias0;
        }
        // ---- layer1: gates for (unit u, all 16 batches) ----
        if (s >= 1) {
            float A[64];
            #pragma unroll
            for (int j = 0; j < 64; ++j) A[j] = 0.0f;
            #pragma unroll
            for (int b = 0; b < BGB; ++b) {
                float4 ha = *(const float4*)&h0_lds[b][l * 4];
                float4 hb = *(const float4*)&h0_lds[b][256 + l * 4];
                float4 qa = *(const float4*)&h2_lds[b][l * 4];
                float4 qb = *(const float4*)&h2_lds[b][256 + l * 4];
                #pragma unroll
                for (int g = 0; g < 4; ++g) {
                    A[g * 16 + b] += dot4(w1i[g][0], ha) + dot4(w1i[g][1], hb)
                                   + dot4(w1h[g][0], qa) + dot4(w1h[g][1], qb);
                }
            }
            r1 = wave_reduce64(A, l) + bias1;
        }

        // ---- gather gates to lanes 0..15 (shfl by ALL lanes), update state ----
        float gi0 = __shfl(r0, bl,      64);
        float gf0 = __shfl(r0, bl + 16, 64);
        float gc0 = __shfl(r0, bl + 32, 64);
        float go0 = __shfl(r0, bl + 48, 64);
        float gi1 = __shfl(r1, bl,      64);
        float gf1 = __shfl(r1, bl + 16, 64);
        float gc1 = __shfl(r1, bl + 32, 64);
        float go1 = __shfl(r1, bl + 48, 64);
        if (l < 16) {
            if (s < TT) {
                float cn = sigf(gf0) * c0r + sigf(gi0) * tanhf(gc0);
                c0r = cn;
                h0T[cur * HD * NB + (size_t)u * NB + bg16 + bl] = sigf(go0) * tanhf(cn);
            }
            if (s >= 1) {
                float cn = sigf(gf1) * c2r + sigf(gi1) * tanhf(gc1);
                c2r = cn;
                h2T[(cur ^ 1) * HD * NB + (size_t)u * NB + bg16 + bl] = sigf(go1) * tanhf(cn);
            }
        }

        // ---- arrive ----
        __syncthreads();
        if (tid == 0) {
            __threadfence();
            __hip_atomic_fetch_add(myflag, 1, __ATOMIC_RELEASE,
                                   __HIP_MEMORY_SCOPE_AGENT);
        }
    }

    // ---------------- FC tail: one block per batch group ----------------
    if (rb != 0) return;
    {
        const int target = RBN * (TT + 1);
        if (tid == 0) {
            int spins = 0;
            while (__hip_atomic_load(myflag, __ATOMIC_RELAXED,
                                     __HIP_MEMORY_SCOPE_AGENT) < target) {
                __builtin_amdgcn_s_sleep(8);
                if (++spins > (1 << 22)) break;
            }
            (void)__hip_atomic_load(myflag, __ATOMIC_ACQUIRE,
                                    __HIP_MEMORY_SCOPE_AGENT);
        }
        __syncthreads();

        // h2[TT-1] lives in buffer (TT-1)&1 = 1
        const float* hsrc = h2T + 1 * HD * NB + (size_t)tid * NB + bg16;
        float4 q0 = *(const float4*)(hsrc + 0),  q1 = *(const float4*)(hsrc + 4);
        float4 q2 = *(const float4*)(hsrc + 8),  q3 = *(const float4*)(hsrc + 12);
        h2_lds[ 0][tid]=q0.x; h2_lds[ 1][tid]=q0.y; h2_lds[ 2][tid]=q0.z; h2_lds[ 3][tid]=q0.w;
        h2_lds[ 4][tid]=q1.x; h2_lds[ 5][tid]=q1.y; h2_lds[ 6][tid]=q1.z; h2_lds[ 7][tid]=q1.w;
        h2_lds[ 8][tid]=q2.x; h2_lds[ 9][tid]=q2.y; h2_lds[10][tid]=q2.z; h2_lds[11][tid]=q2.w;
        h2_lds[12][tid]=q3.x; h2_lds[13][tid]=q3.y; h2_lds[14][tid]=q3.z; h2_lds[15][tid]=q3.w;
        __syncthreads();

        const int bb = tid >> 5, oo = tid & 31;
        if (oo < 24) {
            float acc = fcb[oo];
            const float4* hrow = (const float4*)&h2_lds[bb][0];
            const float4* wrow = (const float4*)(fcW + (size_t)oo * HD);
            #pragma unroll 8
            for (int q = 0; q < HD / 4; ++q) acc += dot4(hrow[q], wrow[q]);
            out[(size_t)(bg16 + bb) * 24 + oo] = acc;
        }
    }
}

extern "C" void kernel_launch(void* const* d_in, const int* in_sizes, int n_in,
                              void* d_out, int out_size, void* d_ws, size_t ws_size,
                              hipStream_t stream)
{
    const float* x    = (const float*)d_in[0];
    const float* Wih0 = (const float*)d_in[1];
    const float* Whh0 = (const float*)d_in[2];
    const float* bih0 = (const float*)d_in[3];
    const float* bhh0 = (const float*)d_in[4];
    const float* Wih1 = (const float*)d_in[5];
    const float* Whh1 = (const float*)d_in[6];
    const float* bih1 = (const float*)d_in[7];
    const float* bhh1 = (const float*)d_in[8];
    const float* fcW  = (const float*)d_in[9];
    const float* fcb  = (const float*)d_in[10];

    // zero h ping-pong buffers + flags every call (graph-capture-safe)
    hipMemsetAsync(d_ws, 0, (size_t)(4 * HD * NB) * sizeof(float) + 1024, stream);

    lstm_persist<<<dim3(BGN * RBN), dim3(512), 0, stream>>>(
        x, Wih0, Whh0, bih0, bhh0, Wih1, Whh1, bih1, bhh1, fcW, fcb,
        (float*)d_ws, (float*)d_out);
}